// Round 7
// baseline (460.362 us; speedup 1.0000x reference)
//
#include <hip/hip_runtime.h>
#include <hip/hip_bf16.h>

#define DIM 128
#define SB 256       // scan block size
#define NA 256       // pass-A blocks for edge sort
#define EAMAX 6272   // padded per-block edge capacity (E/NA = 6250)
#define BCAP 4096    // max edges per 128-node bucket (mean 2048, sd ~45)

typedef __attribute__((ext_vector_type(8))) short bf16x8;
typedef __attribute__((ext_vector_type(4))) float f32x4;

__device__ inline float bf2f(unsigned short u) {
    unsigned v = (unsigned)u << 16;
    union { unsigned u; float f; } c; c.u = v; return c.f;
}
__device__ inline unsigned short f2bf(float f) {
    union { __hip_bfloat16 h; unsigned short u; } c;
    c.h = __float2bfloat16(f);
    return c.u;
}

// ================= graph build: LDS-staged counting sort by dst =================

__global__ __launch_bounds__(256) void k_hist(const int* __restrict__ dst,
                                              int* __restrict__ histG,
                                              int E, int EA, int nbuk) {
    __shared__ int h[1024];
    int t = threadIdx.x, blk = blockIdx.x;
    for (int i = t; i < 1024; i += 256) h[i] = 0;
    __syncthreads();
    int lo = blk * EA, hi = min(E, lo + EA);
    for (int i = lo + t; i < hi; i += 256) atomicAdd(&h[dst[i] >> 7], 1);
    __syncthreads();
    for (int bk = t; bk < nbuk; bk += 256) histG[bk * NA + blk] = h[bk];
}

__global__ __launch_bounds__(SB) void k_scan1(const int* __restrict__ cnt,
                                              int* __restrict__ bsum, int n) {
    int t = threadIdx.x;
    int i = blockIdx.x * SB + t;
    int v = (i < n) ? cnt[i] : 0;
#pragma unroll
    for (int m = 1; m < 64; m <<= 1) v += __shfl_xor(v, m);
    __shared__ int w[SB / 64];
    if ((t & 63) == 0) w[t >> 6] = v;
    __syncthreads();
    if (t == 0) {
        int s = 0;
#pragma unroll
        for (int k = 0; k < SB / 64; ++k) s += w[k];
        bsum[blockIdx.x] = s;
    }
}

__global__ __launch_bounds__(1024) void k_scan2(int* __restrict__ bsum, int B) {
    __shared__ int s[1024];
    int t = threadIdx.x;
    int v = (t < B) ? bsum[t] : 0;
    s[t] = v;
    __syncthreads();
    for (int off = 1; off < 1024; off <<= 1) {
        int u = (t >= off) ? s[t - off] : 0;
        __syncthreads();
        s[t] += u;
        __syncthreads();
    }
    if (t < B) bsum[t] = s[t] - v;  // exclusive
}

__global__ __launch_bounds__(SB) void k_scan3g(const int* __restrict__ cnt,
                                               const int* __restrict__ bsum,
                                               int* __restrict__ outx, int n) {
    __shared__ int s[SB];
    int t = threadIdx.x;
    int i = blockIdx.x * SB + t;
    int c = (i < n) ? cnt[i] : 0;
    s[t] = c;
    __syncthreads();
    for (int off = 1; off < SB; off <<= 1) {
        int u = (t >= off) ? s[t - off] : 0;
        __syncthreads();
        s[t] += u;
        __syncthreads();
    }
    int excl = bsum[blockIdx.x] + s[t] - c;
    if (i < n) {
        outx[i] = excl;
        if (i == n - 1) outx[n] = excl + c;
    }
}

__global__ __launch_bounds__(256) void k_place(const int* __restrict__ src,
                                               const int* __restrict__ dst,
                                               const int* __restrict__ scannedG,
                                               unsigned* __restrict__ ebuf,
                                               int E, int EA, int nbuk) {
    __shared__ int h[1024];
    __shared__ int dl[1024];
    __shared__ int ws4[4];
    __shared__ unsigned srt[EAMAX];
    __shared__ unsigned short bkt[EAMAX];
    int t = threadIdx.x, blk = blockIdx.x;
    int lo = blk * EA, hi = min(E, lo + EA);

    for (int i = t; i < 1024; i += 256) h[i] = 0;
    __syncthreads();
    for (int i = lo + t; i < hi; i += 256) atomicAdd(&h[dst[i] >> 7], 1);
    __syncthreads();

    {
        int b4 = t * 4;
        int v0 = h[b4], v1 = h[b4 + 1], v2 = h[b4 + 2], v3 = h[b4 + 3];
        int i1 = v0 + v1, i2 = i1 + v2, i3 = i2 + v3;
        int lane = t & 63, wv = t >> 6;
        int sc = i3;
#pragma unroll
        for (int o = 1; o < 64; o <<= 1) {
            int u = __shfl_up(sc, o);
            if (lane >= o) sc += u;
        }
        if (lane == 63) ws4[wv] = sc;
        __syncthreads();
        int woff = 0;
#pragma unroll
        for (int k = 0; k < 4; ++k) woff += (k < wv) ? ws4[k] : 0;
        int tex = woff + sc - i3;
        h[b4] = tex; h[b4 + 1] = tex + v0; h[b4 + 2] = tex + i1; h[b4 + 3] = tex + i2;
    }
    __syncthreads();

    for (int bk = t; bk < nbuk; bk += 256)
        dl[bk] = scannedG[bk * NA + blk] - h[bk];
    __syncthreads();

    for (int i = lo + t; i < hi; i += 256) {
        int d = dst[i];
        int bk = d >> 7;
        unsigned p = ((unsigned)(d & 127) << 17) | (unsigned)src[i];
        int r = atomicAdd(&h[bk], 1);
        srt[r] = p;
        bkt[r] = (unsigned short)bk;
    }
    __syncthreads();

    int m = hi - lo;
    for (int i = t; i < m; i += 256)
        ebuf[dl[bkt[i]] + i] = srt[i];
}

__global__ __launch_bounds__(256) void k_finish(const unsigned* __restrict__ ebuf,
                                                const int* __restrict__ scannedG,
                                                int* __restrict__ offs,
                                                float* __restrict__ dinv,
                                                int* __restrict__ csrc,
                                                int n, int nbuk) {
    __shared__ unsigned eds[BCAP];
    __shared__ unsigned srt[BCAP];
    __shared__ int lcnt[128], lcur[128];
    __shared__ int wsum[2];
    int b = blockIdx.x, t = threadIdx.x;
    int e0 = scannedG[b * NA], e1 = scannedG[(b + 1) * NA];
    int m = min(e1 - e0, BCAP);

    for (int i = t; i < m; i += 256) eds[i] = ebuf[e0 + i];
    if (t < 128) lcnt[t] = 0;
    __syncthreads();
    for (int i = t; i < m; i += 256) atomicAdd(&lcnt[eds[i] >> 17], 1);
    __syncthreads();

    int c = (t < 128) ? lcnt[t] : 0;
    int lane = t & 63, wv = t >> 6;
    int s = c;
#pragma unroll
    for (int o = 1; o < 64; o <<= 1) {
        int u = __shfl_up(s, o);
        if (lane >= o) s += u;
    }
    if (lane == 63 && wv < 2) wsum[wv] = s;
    __syncthreads();
    int excl = s - c + ((wv == 1) ? wsum[0] : 0);
    if (t < 128) {
        int node = b * 128 + t;
        if (node < n) {
            offs[node] = e0 + excl;
            dinv[node] = rsqrtf((float)(c + 1));  // +1 self-loop
        }
        lcur[t] = excl;
    }
    if (b == nbuk - 1 && t == 0) offs[n] = e1;
    __syncthreads();

    for (int i = t; i < m; i += 256) {
        unsigned v = eds[i];
        int r = atomicAdd(&lcur[v >> 17], 1);
        srt[r] = v & 0x1FFFFu;
    }
    __syncthreads();
    for (int i = t; i < m; i += 256) csrc[e0 + i] = (int)srt[i];
}

// ================= GEMM via bf16 MFMA (round-5-exact body, slice-major write) =================
// H written SLICE-MAJOR: H[slice nt][node][li]  (slice = 16 dims)

__global__ __launch_bounds__(256) void k_gemm(const float* __restrict__ in,
                                              const float* __restrict__ W,
                                              const float* __restrict__ dinv,
                                              unsigned short* __restrict__ outH, int n) {
    __shared__ unsigned short Wt[DIM * 136];  // W^T bf16, pitch 136
    int t = threadIdx.x;
#pragma unroll
    for (int i = 0; i < 64; ++i) {
        int idx = i * 256 + t;
        int k = idx >> 7, nn = idx & 127;
        Wt[nn * 136 + k] = f2bf(W[idx]);
    }
    __syncthreads();

    int l = t & 63, w = t >> 6;
    int g = l >> 4, li = l & 15;
    int rbase = blockIdx.x * 128 + w * 32;

    f32x4 acc[2][8];
#pragma unroll
    for (int mt = 0; mt < 2; ++mt)
#pragma unroll
        for (int nt = 0; nt < 8; ++nt) acc[mt][nt] = (f32x4)(0.f);

#pragma unroll
    for (int kk = 0; kk < 4; ++kk) {
        bf16x8 a[2];
#pragma unroll
        for (int mt = 0; mt < 2; ++mt) {
            int row = rbase + mt * 16 + li;
            int rr = (row < n) ? row : (n - 1);
            const float* p = in + (size_t)rr * DIM + kk * 32 + g * 8;
            float4 v0 = *(const float4*)p;
            float4 v1 = *(const float4*)(p + 4);
            bf16x8 av;
            av[0] = (short)f2bf(v0.x); av[1] = (short)f2bf(v0.y);
            av[2] = (short)f2bf(v0.z); av[3] = (short)f2bf(v0.w);
            av[4] = (short)f2bf(v1.x); av[5] = (short)f2bf(v1.y);
            av[6] = (short)f2bf(v1.z); av[7] = (short)f2bf(v1.w);
            a[mt] = av;
        }
#pragma unroll
        for (int nt = 0; nt < 8; ++nt) {
            bf16x8 bb = *(const bf16x8*)&Wt[(nt * 16 + li) * 136 + kk * 32 + g * 8];
            acc[0][nt] = __builtin_amdgcn_mfma_f32_16x16x32_bf16(a[0], bb, acc[0][nt], 0, 0, 0);
            acc[1][nt] = __builtin_amdgcn_mfma_f32_16x16x32_bf16(a[1], bb, acc[1][nt], 0, 0, 0);
        }
    }

#pragma unroll
    for (int mt = 0; mt < 2; ++mt)
#pragma unroll
        for (int r = 0; r < 4; ++r) {
            int row = rbase + mt * 16 + g * 4 + r;
            if (row < n) {
                float s = dinv[row];
#pragma unroll
                for (int nt = 0; nt < 8; ++nt)
                    outH[((size_t)nt * n + row) * 16 + li] = f2bf(acc[mt][nt][r] * s);
            }
        }
}

// ================= sliced aggregation: slice = blockIdx & 7 -> XCD-pinned =================
// wave: 8 node-slots x 8 lanes; lane c covers dims (slice*16 + 2c, +1).
// v = dinv[i]*(H[i] + sum_src H[src]) + bias
// MODE 0: relu(v) -> out ; MODE 1: relu(v)+identity -> out ; MODE 2: v -> out

template <int MODE>
__global__ __launch_bounds__(256) void k_aggs(const unsigned* __restrict__ Hs,
                                              const float* __restrict__ dinv,
                                              const int* __restrict__ offs,
                                              const int* __restrict__ csrc,
                                              const float* __restrict__ bias,
                                              const float* __restrict__ identity,
                                              float* __restrict__ out_raw, int n) {
    int sl = blockIdx.x & 7;
    int chunk = blockIdx.x >> 3;
    int wv = threadIdx.x >> 6, lane = threadIdx.x & 63;
    int slot = lane >> 3, c = lane & 7;
    int i = chunk * 32 + wv * 8 + slot;
    bool act = i < n;
    int ii = act ? i : 0;

    const unsigned* base = Hs + (size_t)sl * n * 8;  // 8 uints per node-slice

    unsigned u0 = base[(size_t)ii * 8 + c];  // self loop
    float ax = bf2f((unsigned short)(u0 & 0xffff));
    float ay = bf2f((unsigned short)(u0 >> 16));

    int s0 = offs[ii], e0 = offs[ii + 1];
    if (!act) { s0 = 0; e0 = 0; }
    int j = s0;
    for (; j + 4 <= e0; j += 4) {
        int i0 = csrc[j], i1 = csrc[j + 1], i2 = csrc[j + 2], i3 = csrc[j + 3];
        unsigned v0 = base[(size_t)i0 * 8 + c];
        unsigned v1 = base[(size_t)i1 * 8 + c];
        unsigned v2 = base[(size_t)i2 * 8 + c];
        unsigned v3 = base[(size_t)i3 * 8 + c];
        ax += bf2f((unsigned short)(v0 & 0xffff)); ay += bf2f((unsigned short)(v0 >> 16));
        ax += bf2f((unsigned short)(v1 & 0xffff)); ay += bf2f((unsigned short)(v1 >> 16));
        ax += bf2f((unsigned short)(v2 & 0xffff)); ay += bf2f((unsigned short)(v2 >> 16));
        ax += bf2f((unsigned short)(v3 & 0xffff)); ay += bf2f((unsigned short)(v3 >> 16));
    }
    for (; j < e0; ++j) {
        unsigned v = base[(size_t)csrc[j] * 8 + c];
        ax += bf2f((unsigned short)(v & 0xffff));
        ay += bf2f((unsigned short)(v >> 16));
    }

    int d = sl * 16 + 2 * c;
    float di = dinv[ii];
    float2 bs = *(const float2*)(bias + d);
    float vx = di * ax + bs.x;
    float vy = di * ay + bs.y;

    float xx, xy;
    if (MODE == 0) { xx = fmaxf(vx, 0.f); xy = fmaxf(vy, 0.f); }
    if (MODE == 1) {
        float2 id = *(const float2*)(identity + (size_t)ii * DIM + d);
        xx = fmaxf(vx, 0.f) + id.x;
        xy = fmaxf(vy, 0.f) + id.y;
    }
    if (MODE == 2) { xx = vx; xy = vy; }

    if (act) *(float2*)(out_raw + (size_t)i * DIM + d) = make_float2(xx, xy);
}

// ================= LayerNorm (one wave per row, in- or out-of-place) =================

__global__ __launch_bounds__(256) void k_ln(const float* __restrict__ in,
                                            const float* __restrict__ g,
                                            const float* __restrict__ b,
                                            float* __restrict__ out, int n) {
    int w = threadIdx.x >> 6, lane = threadIdx.x & 63;
    int row = blockIdx.x * 4 + w;
    if (row >= n) return;
    float2 v = ((const float2*)(in + (size_t)row * DIM))[lane];
    float s = v.x + v.y;
#pragma unroll
    for (int m = 1; m < 64; m <<= 1) s += __shfl_xor(s, m);
    float mu = s * (1.f / 128.f);
    float dx = v.x - mu, dy = v.y - mu;
    float q = dx * dx + dy * dy;
#pragma unroll
    for (int m = 1; m < 64; m <<= 1) q += __shfl_xor(q, m);
    float rstd = rsqrtf(q * (1.f / 128.f) + 1e-5f);
    float2 gg = ((const float2*)g)[lane];
    float2 bb = ((const float2*)b)[lane];
    ((float2*)(out + (size_t)row * DIM))[lane] =
        make_float2(dx * rstd * gg.x + bb.x, dy * rstd * gg.y + bb.y);
}

// ================= launch =================

static inline char* alignp(char* p) {
    return (char*)(((size_t)p + 255) & ~(size_t)255);
}

extern "C" void kernel_launch(void* const* d_in, const int* in_sizes, int n_in,
                              void* d_out, int out_size, void* d_ws, size_t ws_size,
                              hipStream_t stream) {
    const float* x   = (const float*)d_in[0];
    const int*   ei  = (const int*)d_in[1];
    const float* W0  = (const float*)d_in[2];
    const float* b0  = (const float*)d_in[3];
    const float* W1  = (const float*)d_in[4];
    const float* b1  = (const float*)d_in[5];
    const float* W2  = (const float*)d_in[6];
    const float* b2  = (const float*)d_in[7];
    const float* lng = (const float*)d_in[8];
    const float* lnb = (const float*)d_in[9];
    const float* fng = (const float*)d_in[10];
    const float* fnb = (const float*)d_in[11];
    float* out = (float*)d_out;

    int n = in_sizes[0] / DIM;       // 100000
    int E = in_sizes[1] / 2;         // 1600000
    const int* src = ei;
    const int* dst = ei + E;

    int nbuk = (n + 127) >> 7;       // 782
    int EA   = (E + NA - 1) / NA;    // 6250
    int nh   = nbuk * NA;            // 200192

    char* p = (char*)d_ws;
    unsigned short* H = (unsigned short*)p;  p = alignp(p + (size_t)n * DIM * 2);
    float* hb   = (float*)p;                 p = alignp(p + (size_t)n * DIM * 4);
    float* dinv = (float*)p;                 p = alignp(p + (size_t)n * 4);
    int*   offs = (int*)p;                   p = alignp(p + (size_t)(n + 1) * 4);
    int*   csrc = (int*)p;                   p = alignp(p + (size_t)E * 4);
    unsigned* ebuf = (unsigned*)p;           p = alignp(p + (size_t)E * 4);
    int*   histG = (int*)p;                  p = alignp(p + (size_t)nh * 4);
    int*   scannedG = (int*)p;               p = alignp(p + (size_t)(nh + 1) * 4);
    int*   bsum = (int*)p;

    int grid_g = (n + 127) / 128;
    int Bs = (nh + SB - 1) / SB;

    // build CSR (counting sort, LDS-staged, no global atomics)
    k_hist<<<NA, 256, 0, stream>>>(dst, histG, E, EA, nbuk);
    k_scan1<<<Bs, SB, 0, stream>>>(histG, bsum, nh);
    k_scan2<<<1, 1024, 0, stream>>>(bsum, Bs);
    k_scan3g<<<Bs, SB, 0, stream>>>(histG, bsum, scannedG, nh);
    k_place<<<NA, 256, 0, stream>>>(src, dst, scannedG, ebuf, E, EA, nbuk);
    k_finish<<<nbuk, 256, 0, stream>>>(ebuf, scannedG, offs, dinv, csrc, n, nbuk);

    const unsigned* H2 = (const unsigned*)H;
    int grid_a = ((n + 31) / 32) * 8;        // chunk x 8 slices
    int grid_l = (n + 3) / 4;

    // layer 0: hb = relu(conv(x))
    k_gemm<<<grid_g, 256, 0, stream>>>(x, W0, dinv, H, n);
    k_aggs<0><<<grid_a, 256, 0, stream>>>(H2, dinv, offs, csrc, b0, nullptr, hb, n);

    // middle: out(temp) = LN(hb); hb = relu(conv(out)) + hb
    k_ln<<<grid_l, 256, 0, stream>>>(hb, lng, lnb, out, n);
    k_gemm<<<grid_g, 256, 0, stream>>>(out, W1, dinv, H, n);
    k_aggs<1><<<grid_a, 256, 0, stream>>>(H2, dinv, offs, csrc, b1, hb, hb, n);

    // final: out = LN(conv(hb))
    k_gemm<<<grid_g, 256, 0, stream>>>(hb, W2, dinv, H, n);
    k_aggs<2><<<grid_a, 256, 0, stream>>>(H2, dinv, offs, csrc, b2, nullptr, out, n);
    k_ln<<<grid_l, 256, 0, stream>>>(out, fng, fnb, out, n);
}

// Round 8
// 347.131 us; speedup vs baseline: 1.3262x; 1.3262x over previous
//
#include <hip/hip_runtime.h>
#include <hip/hip_bf16.h>

#define DIM 128
#define SB 256       // scan block size
#define NA 256       // pass-A blocks for edge sort
#define EAMAX 6272   // padded per-block edge capacity (E/NA = 6250)
#define BCAP 4096    // max edges per 128-node bucket (mean 2048, sd ~45)

typedef __attribute__((ext_vector_type(8))) short bf16x8;
typedef __attribute__((ext_vector_type(4))) float f32x4;

__device__ inline float bf2f(unsigned short u) {
    unsigned v = (unsigned)u << 16;
    union { unsigned u; float f; } c; c.u = v; return c.f;
}
__device__ inline unsigned short f2bf(float f) {
    union { __hip_bfloat16 h; unsigned short u; } c;
    c.h = __float2bfloat16(f);
    return c.u;
}
__device__ inline unsigned pk2(float a, float b) {
    return (unsigned)f2bf(a) | ((unsigned)f2bf(b) << 16);
}

// ================= graph build: LDS-staged counting sort by dst =================

__global__ __launch_bounds__(256) void k_hist(const int* __restrict__ dst,
                                              int* __restrict__ histG,
                                              int E, int EA, int nbuk) {
    __shared__ int h[1024];
    int t = threadIdx.x, blk = blockIdx.x;
    for (int i = t; i < 1024; i += 256) h[i] = 0;
    __syncthreads();
    int lo = blk * EA, hi = min(E, lo + EA);
    for (int i = lo + t; i < hi; i += 256) atomicAdd(&h[dst[i] >> 7], 1);
    __syncthreads();
    for (int bk = t; bk < nbuk; bk += 256) histG[bk * NA + blk] = h[bk];
}

__global__ __launch_bounds__(SB) void k_scan1(const int* __restrict__ cnt,
                                              int* __restrict__ bsum, int n) {
    int t = threadIdx.x;
    int i = blockIdx.x * SB + t;
    int v = (i < n) ? cnt[i] : 0;
#pragma unroll
    for (int m = 1; m < 64; m <<= 1) v += __shfl_xor(v, m);
    __shared__ int w[SB / 64];
    if ((t & 63) == 0) w[t >> 6] = v;
    __syncthreads();
    if (t == 0) {
        int s = 0;
#pragma unroll
        for (int k = 0; k < SB / 64; ++k) s += w[k];
        bsum[blockIdx.x] = s;
    }
}

__global__ __launch_bounds__(1024) void k_scan2(int* __restrict__ bsum, int B) {
    __shared__ int s[1024];
    int t = threadIdx.x;
    int v = (t < B) ? bsum[t] : 0;
    s[t] = v;
    __syncthreads();
    for (int off = 1; off < 1024; off <<= 1) {
        int u = (t >= off) ? s[t - off] : 0;
        __syncthreads();
        s[t] += u;
        __syncthreads();
    }
    if (t < B) bsum[t] = s[t] - v;  // exclusive
}

__global__ __launch_bounds__(SB) void k_scan3g(const int* __restrict__ cnt,
                                               const int* __restrict__ bsum,
                                               int* __restrict__ outx, int n) {
    __shared__ int s[SB];
    int t = threadIdx.x;
    int i = blockIdx.x * SB + t;
    int c = (i < n) ? cnt[i] : 0;
    s[t] = c;
    __syncthreads();
    for (int off = 1; off < SB; off <<= 1) {
        int u = (t >= off) ? s[t - off] : 0;
        __syncthreads();
        s[t] += u;
        __syncthreads();
    }
    int excl = bsum[blockIdx.x] + s[t] - c;
    if (i < n) {
        outx[i] = excl;
        if (i == n - 1) outx[n] = excl + c;
    }
}

__global__ __launch_bounds__(256) void k_place(const int* __restrict__ src,
                                               const int* __restrict__ dst,
                                               const int* __restrict__ scannedG,
                                               unsigned* __restrict__ ebuf,
                                               int E, int EA, int nbuk) {
    __shared__ int h[1024];
    __shared__ int dl[1024];
    __shared__ int ws4[4];
    __shared__ unsigned srt[EAMAX];
    __shared__ unsigned short bkt[EAMAX];
    int t = threadIdx.x, blk = blockIdx.x;
    int lo = blk * EA, hi = min(E, lo + EA);

    for (int i = t; i < 1024; i += 256) h[i] = 0;
    __syncthreads();
    for (int i = lo + t; i < hi; i += 256) atomicAdd(&h[dst[i] >> 7], 1);
    __syncthreads();

    {
        int b4 = t * 4;
        int v0 = h[b4], v1 = h[b4 + 1], v2 = h[b4 + 2], v3 = h[b4 + 3];
        int i1 = v0 + v1, i2 = i1 + v2, i3 = i2 + v3;
        int lane = t & 63, wv = t >> 6;
        int sc = i3;
#pragma unroll
        for (int o = 1; o < 64; o <<= 1) {
            int u = __shfl_up(sc, o);
            if (lane >= o) sc += u;
        }
        if (lane == 63) ws4[wv] = sc;
        __syncthreads();
        int woff = 0;
#pragma unroll
        for (int k = 0; k < 4; ++k) woff += (k < wv) ? ws4[k] : 0;
        int tex = woff + sc - i3;
        h[b4] = tex; h[b4 + 1] = tex + v0; h[b4 + 2] = tex + i1; h[b4 + 3] = tex + i2;
    }
    __syncthreads();

    for (int bk = t; bk < nbuk; bk += 256)
        dl[bk] = scannedG[bk * NA + blk] - h[bk];
    __syncthreads();

    for (int i = lo + t; i < hi; i += 256) {
        int d = dst[i];
        int bk = d >> 7;
        unsigned p = ((unsigned)(d & 127) << 17) | (unsigned)src[i];
        int r = atomicAdd(&h[bk], 1);
        srt[r] = p;
        bkt[r] = (unsigned short)bk;
    }
    __syncthreads();

    int m = hi - lo;
    for (int i = t; i < m; i += 256)
        ebuf[dl[bkt[i]] + i] = srt[i];
}

__global__ __launch_bounds__(256) void k_finish(const unsigned* __restrict__ ebuf,
                                                const int* __restrict__ scannedG,
                                                int* __restrict__ offs,
                                                float* __restrict__ dinv,
                                                int* __restrict__ csrc,
                                                int n, int nbuk) {
    __shared__ unsigned eds[BCAP];
    __shared__ unsigned srt[BCAP];
    __shared__ int lcnt[128], lcur[128];
    __shared__ int wsum[2];
    int b = blockIdx.x, t = threadIdx.x;
    int e0 = scannedG[b * NA], e1 = scannedG[(b + 1) * NA];
    int m = min(e1 - e0, BCAP);

    for (int i = t; i < m; i += 256) eds[i] = ebuf[e0 + i];
    if (t < 128) lcnt[t] = 0;
    __syncthreads();
    for (int i = t; i < m; i += 256) atomicAdd(&lcnt[eds[i] >> 17], 1);
    __syncthreads();

    int c = (t < 128) ? lcnt[t] : 0;
    int lane = t & 63, wv = t >> 6;
    int s = c;
#pragma unroll
    for (int o = 1; o < 64; o <<= 1) {
        int u = __shfl_up(s, o);
        if (lane >= o) s += u;
    }
    if (lane == 63 && wv < 2) wsum[wv] = s;
    __syncthreads();
    int excl = s - c + ((wv == 1) ? wsum[0] : 0);
    if (t < 128) {
        int node = b * 128 + t;
        if (node < n) {
            offs[node] = e0 + excl;
            dinv[node] = rsqrtf((float)(c + 1));  // +1 self-loop
        }
        lcur[t] = excl;
    }
    if (b == nbuk - 1 && t == 0) offs[n] = e1;
    __syncthreads();

    for (int i = t; i < m; i += 256) {
        unsigned v = eds[i];
        int r = atomicAdd(&lcur[v >> 17], 1);
        srt[r] = v & 0x1FFFFu;
    }
    __syncthreads();
    for (int i = t; i < m; i += 256) csrc[e0 + i] = (int)srt[i];
}

// ================= GEMM via bf16 MFMA: H[r] = bf16( dinv[r] * (in[r] @ W) ) =================
// row-major H [node][128] (256B rows — full-line gather granularity)

__global__ __launch_bounds__(256) void k_gemm(const float* __restrict__ in,
                                              const float* __restrict__ W,
                                              const float* __restrict__ dinv,
                                              unsigned short* __restrict__ outH, int n) {
    __shared__ unsigned short Wt[DIM * 136];  // W^T bf16, pitch 136
    int t = threadIdx.x;
#pragma unroll
    for (int i = 0; i < 64; ++i) {
        int idx = i * 256 + t;
        int k = idx >> 7, nn = idx & 127;
        Wt[nn * 136 + k] = f2bf(W[idx]);
    }
    __syncthreads();

    int l = t & 63, w = t >> 6;
    int g = l >> 4, li = l & 15;
    int rbase = blockIdx.x * 128 + w * 32;

    f32x4 acc[2][8];
#pragma unroll
    for (int mt = 0; mt < 2; ++mt)
#pragma unroll
        for (int nt = 0; nt < 8; ++nt) acc[mt][nt] = (f32x4)(0.f);

#pragma unroll
    for (int kk = 0; kk < 4; ++kk) {
        bf16x8 a[2];
#pragma unroll
        for (int mt = 0; mt < 2; ++mt) {
            int row = rbase + mt * 16 + li;
            int rr = (row < n) ? row : (n - 1);
            const float* p = in + (size_t)rr * DIM + kk * 32 + g * 8;
            float4 v0 = *(const float4*)p;
            float4 v1 = *(const float4*)(p + 4);
            bf16x8 av;
            av[0] = (short)f2bf(v0.x); av[1] = (short)f2bf(v0.y);
            av[2] = (short)f2bf(v0.z); av[3] = (short)f2bf(v0.w);
            av[4] = (short)f2bf(v1.x); av[5] = (short)f2bf(v1.y);
            av[6] = (short)f2bf(v1.z); av[7] = (short)f2bf(v1.w);
            a[mt] = av;
        }
#pragma unroll
        for (int nt = 0; nt < 8; ++nt) {
            bf16x8 bb = *(const bf16x8*)&Wt[(nt * 16 + li) * 136 + kk * 32 + g * 8];
            acc[0][nt] = __builtin_amdgcn_mfma_f32_16x16x32_bf16(a[0], bb, acc[0][nt], 0, 0, 0);
            acc[1][nt] = __builtin_amdgcn_mfma_f32_16x16x32_bf16(a[1], bb, acc[1][nt], 0, 0, 0);
        }
    }

#pragma unroll
    for (int mt = 0; mt < 2; ++mt)
#pragma unroll
        for (int r = 0; r < 4; ++r) {
            int row = rbase + mt * 16 + g * 4 + r;
            if (row < n) {
                float s = dinv[row];
#pragma unroll
                for (int nt = 0; nt < 8; ++nt)
                    outH[(size_t)row * DIM + nt * 16 + li] = f2bf(acc[mt][nt][r] * s);
            }
        }
}

// ================= aggregation (+ fused LayerNorm), one wave per node =================
// lane covers dims (2*lane, 2*lane+1) as one uint of 2 bf16.
// v = dinv[i]*(H[i] + sum_src H[src]) + bias
// MODE 0: raw=relu(v) -> out_raw; LN(raw) -> out_ln
// MODE 1: raw=relu(v)+identity -> out_raw
// MODE 2: LN(v) -> out_ln
// Gather batch = 16 independent row-gathers in flight (miss-level parallelism).

template <int MODE>
__global__ __launch_bounds__(256) void k_agg(const unsigned* __restrict__ H2,
                                             const float* __restrict__ dinv,
                                             const int* __restrict__ offs,
                                             const int* __restrict__ csrc,
                                             const float* __restrict__ bias,
                                             const float* __restrict__ identity,
                                             float* __restrict__ out_raw,
                                             float* __restrict__ out_ln,
                                             const float* __restrict__ lg,
                                             const float* __restrict__ lb, int n) {
    int wv = threadIdx.x >> 6, lane = threadIdx.x & 63;
    int i = blockIdx.x * 4 + wv;
    if (i >= n) return;

    unsigned u0 = H2[(size_t)i * 64 + lane];  // self loop
    float ax = bf2f((unsigned short)(u0 & 0xffff));
    float ay = bf2f((unsigned short)(u0 >> 16));

    int s = offs[i], e = offs[i + 1];
    int j = s;
    for (; j + 16 <= e; j += 16) {
        int idx[16];
#pragma unroll
        for (int q = 0; q < 16; ++q) idx[q] = csrc[j + q];
        unsigned uu[16];
#pragma unroll
        for (int q = 0; q < 16; ++q) uu[q] = H2[(size_t)idx[q] * 64 + lane];
#pragma unroll
        for (int q = 0; q < 16; ++q) {
            ax += bf2f((unsigned short)(uu[q] & 0xffff));
            ay += bf2f((unsigned short)(uu[q] >> 16));
        }
    }
    for (; j + 4 <= e; j += 4) {
        unsigned uu[4];
#pragma unroll
        for (int q = 0; q < 4; ++q) uu[q] = H2[(size_t)csrc[j + q] * 64 + lane];
#pragma unroll
        for (int q = 0; q < 4; ++q) {
            ax += bf2f((unsigned short)(uu[q] & 0xffff));
            ay += bf2f((unsigned short)(uu[q] >> 16));
        }
    }
    for (; j < e; ++j) {
        unsigned v = H2[(size_t)csrc[j] * 64 + lane];
        ax += bf2f((unsigned short)(v & 0xffff));
        ay += bf2f((unsigned short)(v >> 16));
    }

    float di = dinv[i];
    float2 bs = ((const float2*)bias)[lane];
    float vx = di * ax + bs.x;
    float vy = di * ay + bs.y;

    float xx, xy;
    if (MODE == 0) { xx = fmaxf(vx, 0.f); xy = fmaxf(vy, 0.f); }
    if (MODE == 1) {
        float2 id = ((const float2*)(identity + (size_t)i * DIM))[lane];
        xx = fmaxf(vx, 0.f) + id.x;
        xy = fmaxf(vy, 0.f) + id.y;
    }
    if (MODE == 2) { xx = vx; xy = vy; }

    if (MODE == 0 || MODE == 1)
        ((float2*)(out_raw + (size_t)i * DIM))[lane] = make_float2(xx, xy);

    if (MODE == 0 || MODE == 2) {
        float su = xx + xy;
#pragma unroll
        for (int m = 1; m < 64; m <<= 1) su += __shfl_xor(su, m);
        float mu = su * (1.f / 128.f);
        float dx = xx - mu, dy = xy - mu;
        float q = dx * dx + dy * dy;
#pragma unroll
        for (int m = 1; m < 64; m <<= 1) q += __shfl_xor(q, m);
        float rstd = rsqrtf(q * (1.f / 128.f) + 1e-5f);
        float2 gg = ((const float2*)lg)[lane];
        float2 bb2 = ((const float2*)lb)[lane];
        ((float2*)(out_ln + (size_t)i * DIM))[lane] =
            make_float2(dx * rstd * gg.x + bb2.x, dy * rstd * gg.y + bb2.y);
    }
}

// ================= launch =================

static inline char* alignp(char* p) {
    return (char*)(((size_t)p + 255) & ~(size_t)255);
}

extern "C" void kernel_launch(void* const* d_in, const int* in_sizes, int n_in,
                              void* d_out, int out_size, void* d_ws, size_t ws_size,
                              hipStream_t stream) {
    const float* x   = (const float*)d_in[0];
    const int*   ei  = (const int*)d_in[1];
    const float* W0  = (const float*)d_in[2];
    const float* b0  = (const float*)d_in[3];
    const float* W1  = (const float*)d_in[4];
    const float* b1  = (const float*)d_in[5];
    const float* W2  = (const float*)d_in[6];
    const float* b2  = (const float*)d_in[7];
    const float* lng = (const float*)d_in[8];
    const float* lnb = (const float*)d_in[9];
    const float* fng = (const float*)d_in[10];
    const float* fnb = (const float*)d_in[11];
    float* out = (float*)d_out;

    int n = in_sizes[0] / DIM;       // 100000
    int E = in_sizes[1] / 2;         // 1600000
    const int* src = ei;
    const int* dst = ei + E;

    int nbuk = (n + 127) >> 7;       // 782
    int EA   = (E + NA - 1) / NA;    // 6250
    int nh   = nbuk * NA;            // 200192

    char* p = (char*)d_ws;
    unsigned short* H = (unsigned short*)p;  p = alignp(p + (size_t)n * DIM * 2);
    float* hb   = (float*)p;                 p = alignp(p + (size_t)n * DIM * 4);
    float* dinv = (float*)p;                 p = alignp(p + (size_t)n * 4);
    int*   offs = (int*)p;                   p = alignp(p + (size_t)(n + 1) * 4);
    int*   csrc = (int*)p;                   p = alignp(p + (size_t)E * 4);
    unsigned* ebuf = (unsigned*)p;           p = alignp(p + (size_t)E * 4);
    int*   histG = (int*)p;                  p = alignp(p + (size_t)nh * 4);
    int*   scannedG = (int*)p;               p = alignp(p + (size_t)(nh + 1) * 4);
    int*   bsum = (int*)p;

    int grid_g = (n + 127) / 128;
    int Bs = (nh + SB - 1) / SB;

    // build CSR (counting sort, LDS-staged, no global atomics)
    k_hist<<<NA, 256, 0, stream>>>(dst, histG, E, EA, nbuk);
    k_scan1<<<Bs, SB, 0, stream>>>(histG, bsum, nh);
    k_scan2<<<1, 1024, 0, stream>>>(bsum, Bs);
    k_scan3g<<<Bs, SB, 0, stream>>>(histG, bsum, scannedG, nh);
    k_place<<<NA, 256, 0, stream>>>(src, dst, scannedG, ebuf, E, EA, nbuk);
    k_finish<<<nbuk, 256, 0, stream>>>(ebuf, scannedG, offs, dinv, csrc, n, nbuk);

    const unsigned* H2 = (const unsigned*)H;
    int grid_a = (n + 3) / 4;

    // layer 0: hb = relu(conv(x)); out(temp) = LN(hb)
    k_gemm<<<grid_g, 256, 0, stream>>>(x, W0, dinv, H, n);
    k_agg<0><<<grid_a, 256, 0, stream>>>(H2, dinv, offs, csrc, b0, nullptr, hb, out, lng, lnb, n);

    // middle: hb = relu(conv(LN)) + hb
    k_gemm<<<grid_g, 256, 0, stream>>>(out, W1, dinv, H, n);
    k_agg<1><<<grid_a, 256, 0, stream>>>(H2, dinv, offs, csrc, b1, hb, hb, nullptr, nullptr, nullptr, n);

    // final: out = LN(conv(hb))
    k_gemm<<<grid_g, 256, 0, stream>>>(hb, W2, dinv, H, n);
    k_agg<2><<<grid_a, 256, 0, stream>>>(H2, dinv, offs, csrc, b2, nullptr, nullptr, out, fng, fnb, n);
}

// Round 9
// 332.020 us; speedup vs baseline: 1.3866x; 1.0455x over previous
//
#include <hip/hip_runtime.h>
#include <hip/hip_bf16.h>

#define DIM 128
#define SB 256       // scan block size
#define NA 256       // pass-A blocks for edge sort
#define EAMAX 6272   // padded per-block edge capacity (E/NA = 6250)
#define BCAP 4096    // max edges per 128-node bucket (mean 2048, sd ~45)

typedef __attribute__((ext_vector_type(8))) short bf16x8;
typedef __attribute__((ext_vector_type(4))) float f32x4;

__device__ inline float bf2f(unsigned short u) {
    unsigned v = (unsigned)u << 16;
    union { unsigned u; float f; } c; c.u = v; return c.f;
}
__device__ inline unsigned short f2bf(float f) {
    union { __hip_bfloat16 h; unsigned short u; } c;
    c.h = __float2bfloat16(f);
    return c.u;
}
__device__ inline unsigned pk2(float a, float b) {
    return (unsigned)f2bf(a) | ((unsigned)f2bf(b) << 16);
}

// ================= graph build: LDS-staged counting sort by dst =================

__global__ __launch_bounds__(256) void k_hist(const int* __restrict__ dst,
                                              int* __restrict__ histG,
                                              int E, int EA, int nbuk) {
    __shared__ int h[1024];
    int t = threadIdx.x, blk = blockIdx.x;
    for (int i = t; i < 1024; i += 256) h[i] = 0;
    __syncthreads();
    int lo = blk * EA, hi = min(E, lo + EA);
    for (int i = lo + t; i < hi; i += 256) atomicAdd(&h[dst[i] >> 7], 1);
    __syncthreads();
    for (int bk = t; bk < nbuk; bk += 256) histG[bk * NA + blk] = h[bk];
}

__global__ __launch_bounds__(SB) void k_scan1(const int* __restrict__ cnt,
                                              int* __restrict__ bsum, int n) {
    int t = threadIdx.x;
    int i = blockIdx.x * SB + t;
    int v = (i < n) ? cnt[i] : 0;
#pragma unroll
    for (int m = 1; m < 64; m <<= 1) v += __shfl_xor(v, m);
    __shared__ int w[SB / 64];
    if ((t & 63) == 0) w[t >> 6] = v;
    __syncthreads();
    if (t == 0) {
        int s = 0;
#pragma unroll
        for (int k = 0; k < SB / 64; ++k) s += w[k];
        bsum[blockIdx.x] = s;
    }
}

__global__ __launch_bounds__(1024) void k_scan2(int* __restrict__ bsum, int B) {
    __shared__ int s[1024];
    int t = threadIdx.x;
    int v = (t < B) ? bsum[t] : 0;
    s[t] = v;
    __syncthreads();
    for (int off = 1; off < 1024; off <<= 1) {
        int u = (t >= off) ? s[t - off] : 0;
        __syncthreads();
        s[t] += u;
        __syncthreads();
    }
    if (t < B) bsum[t] = s[t] - v;  // exclusive
}

__global__ __launch_bounds__(SB) void k_scan3g(const int* __restrict__ cnt,
                                               const int* __restrict__ bsum,
                                               int* __restrict__ outx, int n) {
    __shared__ int s[SB];
    int t = threadIdx.x;
    int i = blockIdx.x * SB + t;
    int c = (i < n) ? cnt[i] : 0;
    s[t] = c;
    __syncthreads();
    for (int off = 1; off < SB; off <<= 1) {
        int u = (t >= off) ? s[t - off] : 0;
        __syncthreads();
        s[t] += u;
        __syncthreads();
    }
    int excl = bsum[blockIdx.x] + s[t] - c;
    if (i < n) {
        outx[i] = excl;
        if (i == n - 1) outx[n] = excl + c;
    }
}

__global__ __launch_bounds__(256) void k_place(const int* __restrict__ src,
                                               const int* __restrict__ dst,
                                               const int* __restrict__ scannedG,
                                               unsigned* __restrict__ ebuf,
                                               int E, int EA, int nbuk) {
    __shared__ int h[1024];
    __shared__ int dl[1024];
    __shared__ int ws4[4];
    __shared__ unsigned srt[EAMAX];
    __shared__ unsigned short bkt[EAMAX];
    int t = threadIdx.x, blk = blockIdx.x;
    int lo = blk * EA, hi = min(E, lo + EA);

    for (int i = t; i < 1024; i += 256) h[i] = 0;
    __syncthreads();
    for (int i = lo + t; i < hi; i += 256) atomicAdd(&h[dst[i] >> 7], 1);
    __syncthreads();

    {
        int b4 = t * 4;
        int v0 = h[b4], v1 = h[b4 + 1], v2 = h[b4 + 2], v3 = h[b4 + 3];
        int i1 = v0 + v1, i2 = i1 + v2, i3 = i2 + v3;
        int lane = t & 63, wv = t >> 6;
        int sc = i3;
#pragma unroll
        for (int o = 1; o < 64; o <<= 1) {
            int u = __shfl_up(sc, o);
            if (lane >= o) sc += u;
        }
        if (lane == 63) ws4[wv] = sc;
        __syncthreads();
        int woff = 0;
#pragma unroll
        for (int k = 0; k < 4; ++k) woff += (k < wv) ? ws4[k] : 0;
        int tex = woff + sc - i3;
        h[b4] = tex; h[b4 + 1] = tex + v0; h[b4 + 2] = tex + i1; h[b4 + 3] = tex + i2;
    }
    __syncthreads();

    for (int bk = t; bk < nbuk; bk += 256)
        dl[bk] = scannedG[bk * NA + blk] - h[bk];
    __syncthreads();

    for (int i = lo + t; i < hi; i += 256) {
        int d = dst[i];
        int bk = d >> 7;
        unsigned p = ((unsigned)(d & 127) << 17) | (unsigned)src[i];
        int r = atomicAdd(&h[bk], 1);
        srt[r] = p;
        bkt[r] = (unsigned short)bk;
    }
    __syncthreads();

    int m = hi - lo;
    for (int i = t; i < m; i += 256)
        ebuf[dl[bkt[i]] + i] = srt[i];
}

__global__ __launch_bounds__(256) void k_finish(const unsigned* __restrict__ ebuf,
                                                const int* __restrict__ scannedG,
                                                int* __restrict__ offs,
                                                float* __restrict__ dinv,
                                                int* __restrict__ csrc,
                                                int n, int nbuk) {
    __shared__ unsigned eds[BCAP];
    __shared__ unsigned srt[BCAP];
    __shared__ int lcnt[128], lcur[128];
    __shared__ int wsum[2];
    int b = blockIdx.x, t = threadIdx.x;
    int e0 = scannedG[b * NA], e1 = scannedG[(b + 1) * NA];
    int m = min(e1 - e0, BCAP);

    for (int i = t; i < m; i += 256) eds[i] = ebuf[e0 + i];
    if (t < 128) lcnt[t] = 0;
    __syncthreads();
    for (int i = t; i < m; i += 256) atomicAdd(&lcnt[eds[i] >> 17], 1);
    __syncthreads();

    int c = (t < 128) ? lcnt[t] : 0;
    int lane = t & 63, wv = t >> 6;
    int s = c;
#pragma unroll
    for (int o = 1; o < 64; o <<= 1) {
        int u = __shfl_up(s, o);
        if (lane >= o) s += u;
    }
    if (lane == 63 && wv < 2) wsum[wv] = s;
    __syncthreads();
    int excl = s - c + ((wv == 1) ? wsum[0] : 0);
    if (t < 128) {
        int node = b * 128 + t;
        if (node < n) {
            offs[node] = e0 + excl;
            dinv[node] = rsqrtf((float)(c + 1));  // +1 self-loop
        }
        lcur[t] = excl;
    }
    if (b == nbuk - 1 && t == 0) offs[n] = e1;
    __syncthreads();

    for (int i = t; i < m; i += 256) {
        unsigned v = eds[i];
        int r = atomicAdd(&lcur[v >> 17], 1);
        srt[r] = v & 0x1FFFFu;
    }
    __syncthreads();
    for (int i = t; i < m; i += 256) csrc[e0 + i] = (int)srt[i];
}

// ================= GEMM via bf16 MFMA: H[r] = bf16( dinv[r] * (in[r] @ W) ) =================
// BF=0: fp32 input rows; BF=1: bf16 input rows (direct reinterpret, no convert).
// row-major H [node][128] (256B rows — full-line gather granularity)

template <int BF>
__global__ __launch_bounds__(256) void k_gemm(const void* __restrict__ inp,
                                              const float* __restrict__ W,
                                              const float* __restrict__ dinv,
                                              unsigned short* __restrict__ outH, int n) {
    __shared__ unsigned short Wt[DIM * 136];  // W^T bf16, pitch 136
    int t = threadIdx.x;
#pragma unroll
    for (int i = 0; i < 64; ++i) {
        int idx = i * 256 + t;
        int k = idx >> 7, nn = idx & 127;
        Wt[nn * 136 + k] = f2bf(W[idx]);
    }
    __syncthreads();

    int l = t & 63, w = t >> 6;
    int g = l >> 4, li = l & 15;
    int rbase = blockIdx.x * 128 + w * 32;

    f32x4 acc[2][8];
#pragma unroll
    for (int mt = 0; mt < 2; ++mt)
#pragma unroll
        for (int nt = 0; nt < 8; ++nt) acc[mt][nt] = (f32x4)(0.f);

#pragma unroll
    for (int kk = 0; kk < 4; ++kk) {
        bf16x8 a[2];
#pragma unroll
        for (int mt = 0; mt < 2; ++mt) {
            int row = rbase + mt * 16 + li;
            int rr = (row < n) ? row : (n - 1);
            if (BF) {
                const unsigned short* pb =
                    (const unsigned short*)inp + (size_t)rr * DIM + kk * 32 + g * 8;
                a[mt] = *(const bf16x8*)pb;
            } else {
                const float* p = (const float*)inp + (size_t)rr * DIM + kk * 32 + g * 8;
                float4 v0 = *(const float4*)p;
                float4 v1 = *(const float4*)(p + 4);
                bf16x8 av;
                av[0] = (short)f2bf(v0.x); av[1] = (short)f2bf(v0.y);
                av[2] = (short)f2bf(v0.z); av[3] = (short)f2bf(v0.w);
                av[4] = (short)f2bf(v1.x); av[5] = (short)f2bf(v1.y);
                av[6] = (short)f2bf(v1.z); av[7] = (short)f2bf(v1.w);
                a[mt] = av;
            }
        }
#pragma unroll
        for (int nt = 0; nt < 8; ++nt) {
            bf16x8 bb = *(const bf16x8*)&Wt[(nt * 16 + li) * 136 + kk * 32 + g * 8];
            acc[0][nt] = __builtin_amdgcn_mfma_f32_16x16x32_bf16(a[0], bb, acc[0][nt], 0, 0, 0);
            acc[1][nt] = __builtin_amdgcn_mfma_f32_16x16x32_bf16(a[1], bb, acc[1][nt], 0, 0, 0);
        }
    }

#pragma unroll
    for (int mt = 0; mt < 2; ++mt)
#pragma unroll
        for (int r = 0; r < 4; ++r) {
            int row = rbase + mt * 16 + g * 4 + r;
            if (row < n) {
                float s = dinv[row];
#pragma unroll
                for (int nt = 0; nt < 8; ++nt)
                    outH[(size_t)row * DIM + nt * 16 + li] = f2bf(acc[mt][nt][r] * s);
            }
        }
}

// ================= aggregation (+ fused LayerNorm), one wave per node =================
// lane covers dims (2*lane, 2*lane+1) as one uint of 2 bf16.
// v = dinv[i]*(H[i] + sum_src H[src]) + bias ; all intermediate states bf16.
// MODE 0: raw=relu(v) -> rawbf; LN(raw,fp32) -> lnbf
// MODE 1: raw=relu(v)+identity(bf16) -> rawbf
// MODE 2: LN(v) -> outf (fp32, final output)

template <int MODE>
__global__ __launch_bounds__(256) void k_agg(const unsigned* __restrict__ H2,
                                             const float* __restrict__ dinv,
                                             const int* __restrict__ offs,
                                             const int* __restrict__ csrc,
                                             const float* __restrict__ bias,
                                             const unsigned* __restrict__ idbf,
                                             unsigned* __restrict__ rawbf,
                                             unsigned* __restrict__ lnbf,
                                             float* __restrict__ outf,
                                             const float* __restrict__ lg,
                                             const float* __restrict__ lb, int n) {
    int wv = threadIdx.x >> 6, lane = threadIdx.x & 63;
    int i = blockIdx.x * 4 + wv;
    if (i >= n) return;

    unsigned u0 = H2[(size_t)i * 64 + lane];  // self loop
    float ax = bf2f((unsigned short)(u0 & 0xffff));
    float ay = bf2f((unsigned short)(u0 >> 16));

    int s = offs[i], e = offs[i + 1];
    int j = s;
    for (; j + 16 <= e; j += 16) {
        int idx[16];
#pragma unroll
        for (int q = 0; q < 16; ++q) idx[q] = csrc[j + q];
        unsigned uu[16];
#pragma unroll
        for (int q = 0; q < 16; ++q) uu[q] = H2[(size_t)idx[q] * 64 + lane];
#pragma unroll
        for (int q = 0; q < 16; ++q) {
            ax += bf2f((unsigned short)(uu[q] & 0xffff));
            ay += bf2f((unsigned short)(uu[q] >> 16));
        }
    }
    for (; j + 4 <= e; j += 4) {
        unsigned uu[4];
#pragma unroll
        for (int q = 0; q < 4; ++q) uu[q] = H2[(size_t)csrc[j + q] * 64 + lane];
#pragma unroll
        for (int q = 0; q < 4; ++q) {
            ax += bf2f((unsigned short)(uu[q] & 0xffff));
            ay += bf2f((unsigned short)(uu[q] >> 16));
        }
    }
    for (; j < e; ++j) {
        unsigned v = H2[(size_t)csrc[j] * 64 + lane];
        ax += bf2f((unsigned short)(v & 0xffff));
        ay += bf2f((unsigned short)(v >> 16));
    }

    float di = dinv[i];
    float2 bs = ((const float2*)bias)[lane];
    float vx = di * ax + bs.x;
    float vy = di * ay + bs.y;

    float xx, xy;
    if (MODE == 0) { xx = fmaxf(vx, 0.f); xy = fmaxf(vy, 0.f); }
    if (MODE == 1) {
        unsigned idu = idbf[(size_t)i * 64 + lane];
        xx = fmaxf(vx, 0.f) + bf2f((unsigned short)(idu & 0xffff));
        xy = fmaxf(vy, 0.f) + bf2f((unsigned short)(idu >> 16));
    }
    if (MODE == 2) { xx = vx; xy = vy; }

    if (MODE == 0 || MODE == 1)
        rawbf[(size_t)i * 64 + lane] = pk2(xx, xy);

    if (MODE == 0 || MODE == 2) {
        float su = xx + xy;
#pragma unroll
        for (int m = 1; m < 64; m <<= 1) su += __shfl_xor(su, m);
        float mu = su * (1.f / 128.f);
        float dx = xx - mu, dy = xy - mu;
        float q = dx * dx + dy * dy;
#pragma unroll
        for (int m = 1; m < 64; m <<= 1) q += __shfl_xor(q, m);
        float rstd = rsqrtf(q * (1.f / 128.f) + 1e-5f);
        float2 gg = ((const float2*)lg)[lane];
        float2 bb2 = ((const float2*)lb)[lane];
        float ox = dx * rstd * gg.x + bb2.x;
        float oy = dy * rstd * gg.y + bb2.y;
        if (MODE == 0)
            lnbf[(size_t)i * 64 + lane] = pk2(ox, oy);
        else
            ((float2*)(outf + (size_t)i * DIM))[lane] = make_float2(ox, oy);
    }
}

// ================= launch =================

static inline char* alignp(char* p) {
    return (char*)(((size_t)p + 255) & ~(size_t)255);
}

extern "C" void kernel_launch(void* const* d_in, const int* in_sizes, int n_in,
                              void* d_out, int out_size, void* d_ws, size_t ws_size,
                              hipStream_t stream) {
    const float* x   = (const float*)d_in[0];
    const int*   ei  = (const int*)d_in[1];
    const float* W0  = (const float*)d_in[2];
    const float* b0  = (const float*)d_in[3];
    const float* W1  = (const float*)d_in[4];
    const float* b1  = (const float*)d_in[5];
    const float* W2  = (const float*)d_in[6];
    const float* b2  = (const float*)d_in[7];
    const float* lng = (const float*)d_in[8];
    const float* lnb = (const float*)d_in[9];
    const float* fng = (const float*)d_in[10];
    const float* fnb = (const float*)d_in[11];
    float* out = (float*)d_out;

    int n = in_sizes[0] / DIM;       // 100000
    int E = in_sizes[1] / 2;         // 1600000
    const int* src = ei;
    const int* dst = ei + E;

    int nbuk = (n + 127) >> 7;       // 782
    int EA   = (E + NA - 1) / NA;    // 6250
    int nh   = nbuk * NA;            // 200192

    char* p = (char*)d_ws;
    unsigned short* H  = (unsigned short*)p; p = alignp(p + (size_t)n * DIM * 2);  // bf16 gather buf
    unsigned* hb  = (unsigned*)p;            p = alignp(p + (size_t)n * DIM * 2);  // bf16 layer state
    unsigned* lno = (unsigned*)p;            p = alignp(p + (size_t)n * DIM * 2);  // bf16 LN temp
    float* dinv = (float*)p;                 p = alignp(p + (size_t)n * 4);
    int*   offs = (int*)p;                   p = alignp(p + (size_t)(n + 1) * 4);
    int*   csrc = (int*)p;                   p = alignp(p + (size_t)E * 4);
    unsigned* ebuf = (unsigned*)p;           p = alignp(p + (size_t)E * 4);
    int*   histG = (int*)p;                  p = alignp(p + (size_t)nh * 4);
    int*   scannedG = (int*)p;               p = alignp(p + (size_t)(nh + 1) * 4);
    int*   bsum = (int*)p;

    int grid_g = (n + 127) / 128;
    int Bs = (nh + SB - 1) / SB;

    // build CSR (counting sort, LDS-staged, no global atomics)
    k_hist<<<NA, 256, 0, stream>>>(dst, histG, E, EA, nbuk);
    k_scan1<<<Bs, SB, 0, stream>>>(histG, bsum, nh);
    k_scan2<<<1, 1024, 0, stream>>>(bsum, Bs);
    k_scan3g<<<Bs, SB, 0, stream>>>(histG, bsum, scannedG, nh);
    k_place<<<NA, 256, 0, stream>>>(src, dst, scannedG, ebuf, E, EA, nbuk);
    k_finish<<<nbuk, 256, 0, stream>>>(ebuf, scannedG, offs, dinv, csrc, n, nbuk);

    const unsigned* H2 = (const unsigned*)H;
    int grid_a = (n + 3) / 4;

    // layer 0: hb = relu(conv(x)) [bf16]; lno = LN(hb) [bf16]
    k_gemm<0><<<grid_g, 256, 0, stream>>>(x, W0, dinv, H, n);
    k_agg<0><<<grid_a, 256, 0, stream>>>(H2, dinv, offs, csrc, b0, nullptr,
                                         hb, lno, nullptr, lng, lnb, n);

    // middle: hb = relu(conv(lno)) + hb
    k_gemm<1><<<grid_g, 256, 0, stream>>>(lno, W1, dinv, H, n);
    k_agg<1><<<grid_a, 256, 0, stream>>>(H2, dinv, offs, csrc, b1, hb,
                                         hb, nullptr, nullptr, nullptr, nullptr, n);

    // final: out = LN(conv(hb))
    k_gemm<1><<<grid_g, 256, 0, stream>>>(hb, W2, dinv, H, n);
    k_agg<2><<<grid_a, 256, 0, stream>>>(H2, dinv, offs, csrc, b2, nullptr,
                                         nullptr, nullptr, out, fng, fnb, n);
}